// Round 9
// baseline (287.417 us; speedup 1.0000x reference)
//
#include <hip/hip_runtime.h>
#include <hip/hip_bf16.h>

typedef unsigned int uint;
typedef unsigned short ushortT;
typedef __attribute__((ext_vector_type(8))) short bf16x8;
typedef __attribute__((ext_vector_type(4))) float f32x4;

#define S_ 128
#define R_ 384
#define CM 256
#define CZ 128
#define H_ 8
#define D_ 32
#define SR (S_*R_)          // 49152
#define RRTOT (R_*R_)       // 147456
#define SHRD (S_*H_*R_*D_)  // 12582912 elements

__device__ __forceinline__ float bf2f(ushortT u) {
    return __uint_as_float(((uint)u) << 16);
}
__device__ __forceinline__ ushortT f2bf(float f) {
    uint x = __float_as_uint(f);
    x += 0x7FFFu + ((x >> 16) & 1u);   // RNE
    return (ushortT)(x >> 16);
}
__device__ __forceinline__ uint pack_bf2(float lo, float hi) {
    return (uint)f2bf(lo) | ((uint)f2bf(hi) << 16);
}

// ---------------------------------------------------------------------------
// K0: weight prep — transpose + bf16-ify all projection weights.
// ---------------------------------------------------------------------------
__global__ __launch_bounds__(256) void k_prep(
        const float* __restrict__ wq, const float* __restrict__ wk,
        const float* __restrict__ wv, const float* __restrict__ wg,
        const float* __restrict__ wo,
        ushortT* __restrict__ wt, ushortT* __restrict__ wgt,
        ushortT* __restrict__ wot) {
    int id = blockIdx.x * 256 + threadIdx.x;      // 5*65536 total
    int which = id >> 16, r16 = id & 65535;
    int y = r16 & 255, x = r16 >> 8;              // y = coalesced src fast dim
    if (which == 0)      wt[(size_t)y*256 + x]       = f2bf(wq[(size_t)x*256 + y] * 0.17677669529663687f);
    else if (which == 1) wt[(size_t)(256+y)*256 + x] = f2bf(wk[(size_t)x*256 + y]);
    else if (which == 2) wt[(size_t)(512+y)*256 + x] = f2bf(wv[(size_t)x*256 + y]);
    else if (which == 3) wgt[(size_t)y*256 + x]      = f2bf(wg[(size_t)x*256 + y]);
    else                 wot[(size_t)y*256 + x]      = f2bf(wo[(size_t)x*256 + y]);
}

// ---------------------------------------------------------------------------
// K1: pair LN + projection to z[h][i][j] (bf16). One wave per (i,j) row.
// ---------------------------------------------------------------------------
__global__ __launch_bounds__(256) void k_pair_bias(
        const float* __restrict__ pair, const float* __restrict__ pn_g,
        const float* __restrict__ pn_b, const float* __restrict__ w_pair,
        ushortT* __restrict__ z) {
    int wave = threadIdx.x >> 6, lane = threadIdx.x & 63;
    int row = blockIdx.x * 4 + wave;              // [0, R*R)
    const float* x = pair + (size_t)row * CZ;
    float2 xv = *(const float2*)&x[lane * 2];
    float s  = xv.x + xv.y;
    float s2 = xv.x*xv.x + xv.y*xv.y;
    #pragma unroll
    for (int off = 32; off; off >>= 1) {
        s  += __shfl_xor(s,  off);
        s2 += __shfl_xor(s2, off);
    }
    float mu  = s * (1.0f / 128.0f);
    float var = s2 * (1.0f / 128.0f) - mu * mu;
    float rstd = rsqrtf(var + 1e-5f);
    float2 gv = *(const float2*)&pn_g[lane * 2];
    float2 bv = *(const float2*)&pn_b[lane * 2];
    float n0 = (xv.x - mu) * rstd * gv.x + bv.x;
    float n1 = (xv.y - mu) * rstd * gv.y + bv.y;
    float4 wa = *(const float4*)&w_pair[lane*16     ];
    float4 wb = *(const float4*)&w_pair[lane*16 +  4];
    float4 wc = *(const float4*)&w_pair[lane*16 +  8];
    float4 wd = *(const float4*)&w_pair[lane*16 + 12];
    float v0_ = n0*wa.x + n1*wc.x, v1_ = n0*wa.y + n1*wc.y;
    float v2_ = n0*wa.z + n1*wc.z, v3_ = n0*wa.w + n1*wc.w;
    float v4_ = n0*wb.x + n1*wd.x, v5_ = n0*wb.y + n1*wd.y;
    float v6_ = n0*wb.z + n1*wd.z, v7_ = n0*wb.w + n1*wd.w;
    float x0 = __shfl_xor(v0_,1), x1 = __shfl_xor(v1_,1), x2 = __shfl_xor(v2_,1), x3 = __shfl_xor(v3_,1);
    float x4 = __shfl_xor(v4_,1), x5 = __shfl_xor(v5_,1), x6 = __shfl_xor(v6_,1), x7 = __shfl_xor(v7_,1);
    bool b0 = (lane & 1) != 0;
    float u0 = b0 ? v4_+x4 : v0_+x0;
    float u1 = b0 ? v5_+x5 : v1_+x1;
    float u2 = b0 ? v6_+x6 : v2_+x2;
    float u3 = b0 ? v7_+x7 : v3_+x3;
    float y0 = __shfl_xor(u0,2), y1 = __shfl_xor(u1,2), y2 = __shfl_xor(u2,2), y3 = __shfl_xor(u3,2);
    bool b1 = (lane & 2) != 0;
    float w0 = b1 ? u2+y2 : u0+y0;
    float w1 = b1 ? u3+y3 : u1+y1;
    float z0 = __shfl_xor(w0,4), z1 = __shfl_xor(w1,4);
    bool b2 = (lane & 4) != 0;
    float val = b2 ? w1+z1 : w0+z0;
    val += __shfl_xor(val, 8);
    val += __shfl_xor(val, 16);
    val += __shfl_xor(val, 32);
    int hmap = 4*(lane & 1) + 2*((lane >> 1) & 1) + ((lane >> 2) & 1);
    if (lane < 8) z[(size_t)hmap * RRTOT + row] = f2bf(val);
}

// ---------------------------------------------------------------------------
// LN helper: fused sum/sum^2 single butterfly (E[x^2]-mu^2), float4 loads,
// writes verified XOR-swizzled bf16 layout.
// ---------------------------------------------------------------------------
__device__ __forceinline__ void ln_row_f4(
        const float* __restrict__ src, const float* __restrict__ gam,
        const float* __restrict__ bet, char* msb, int row, int lane) {
    float4 xv = *(const float4*)&src[lane * 4];
    float sm = (xv.x + xv.y) + (xv.z + xv.w);
    float s2 = (xv.x*xv.x + xv.y*xv.y) + (xv.z*xv.z + xv.w*xv.w);
    #pragma unroll
    for (int off = 32; off; off >>= 1) {
        sm += __shfl_xor(sm, off);
        s2 += __shfl_xor(s2, off);
    }
    float mu  = sm * (1.0f / 256.0f);
    float var = s2 * (1.0f / 256.0f) - mu * mu;
    float rstd = rsqrtf(var + 1e-5f);
    float4 gv = *(const float4*)&gam[lane * 4];
    float4 bv = *(const float4*)&bet[lane * 4];
    float n0 = (xv.x - mu) * rstd * gv.x + bv.x, n1 = (xv.y - mu) * rstd * gv.y + bv.y;
    float n2 = (xv.z - mu) * rstd * gv.z + bv.z, n3 = (xv.w - mu) * rstd * gv.w + bv.w;
    uint2 w; w.x = pack_bf2(n0, n1); w.y = pack_bf2(n2, n3);
    *(uint2*)(msb + ((row*512 + lane*8) ^ ((row & 7) << 4))) = w;
}

// ---------------------------------------------------------------------------
// K2: MSA LN + Q/K/V projections via MFMA. 32 rows/block, 4 waves.
// Wave computes 4 col-tiles per mI in ONE group (32 loads in flight, 64 MFMA)
// -> 3 serial groups per block instead of 6. LDS-staged coalesced stores.
// ---------------------------------------------------------------------------
__global__ __launch_bounds__(256) void k_msa_qkv(
        const float* __restrict__ msa, const float* __restrict__ qn_g,
        const float* __restrict__ qn_b, const ushortT* __restrict__ wt,
        ushortT* __restrict__ qo, ushortT* __restrict__ ko,
        ushortT* __restrict__ vto) {
    __shared__ ushortT m_sh[32 * 256];            // LN'd input, XOR (row&7)<<4
    __shared__ ushortT o_sh[32 * 256];            // output staging
    int tid = threadIdx.x, wave = tid >> 6, lane = tid & 63;
    int c = lane & 15, g = (lane >> 4) & 3;
    int r0 = blockIdx.x * 32, s = r0 / R_, rl0 = r0 % R_;
    char* msb = (char*)m_sh;
    char* osb = (char*)o_sh;

    #pragma unroll
    for (int i = 0; i < 8; ++i) {                 // LN: wave handles 8 rows
        int row = wave * 8 + i;
        ln_row_f4(msa + (size_t)(r0 + row) * CM, qn_g, qn_b, msb, row, lane);
    }
    __syncthreads();

    bf16x8 af[2][8];
    #pragma unroll
    for (int rt = 0; rt < 2; ++rt)
        #pragma unroll
        for (int kc = 0; kc < 8; ++kc) {
            int row = rt*16 + c;
            af[rt][kc] = *(const bf16x8*)(msb + ((row*512 + (kc*32 + 8*g)*2) ^ ((c & 7) << 4)));
        }

    const f32x4 z4 = {0.f, 0.f, 0.f, 0.f};
    for (int mI = 0; mI < 3; ++mI) {
        int tb = wave * 4;                        // tiles tb..tb+3 (16/4 waves)
        const ushortT* wb0 = wt + ((size_t)(mI*256 + tb*16 + c)) * 256 + 8*g;
        const ushortT* wb1 = wb0 + 16*256;
        const ushortT* wb2 = wb0 + 32*256;
        const ushortT* wb3 = wb0 + 48*256;
        f32x4 a0L = z4, a0H = z4, a1L = z4, a1H = z4;
        f32x4 a2L = z4, a2H = z4, a3L = z4, a3H = z4;
        #pragma unroll
        for (int kc = 0; kc < 8; ++kc) {
            bf16x8 b0 = *(const bf16x8*)(wb0 + kc*32);
            bf16x8 b1 = *(const bf16x8*)(wb1 + kc*32);
            bf16x8 b2 = *(const bf16x8*)(wb2 + kc*32);
            bf16x8 b3 = *(const bf16x8*)(wb3 + kc*32);
            a0L = __builtin_amdgcn_mfma_f32_16x16x32_bf16(af[0][kc], b0, a0L, 0, 0, 0);
            a0H = __builtin_amdgcn_mfma_f32_16x16x32_bf16(af[1][kc], b0, a0H, 0, 0, 0);
            a1L = __builtin_amdgcn_mfma_f32_16x16x32_bf16(af[0][kc], b1, a1L, 0, 0, 0);
            a1H = __builtin_amdgcn_mfma_f32_16x16x32_bf16(af[1][kc], b1, a1H, 0, 0, 0);
            a2L = __builtin_amdgcn_mfma_f32_16x16x32_bf16(af[0][kc], b2, a2L, 0, 0, 0);
            a2H = __builtin_amdgcn_mfma_f32_16x16x32_bf16(af[1][kc], b2, a2H, 0, 0, 0);
            a3L = __builtin_amdgcn_mfma_f32_16x16x32_bf16(af[0][kc], b3, a3L, 0, 0, 0);
            a3H = __builtin_amdgcn_mfma_f32_16x16x32_bf16(af[1][kc], b3, a3H, 0, 0, 0);
        }
        #pragma unroll
        for (int j = 0; j < 4; ++j) {
            f32x4 lo = (j == 0) ? a0L : (j == 1) ? a1L : (j == 2) ? a2L : a3L;
            f32x4 hi = (j == 0) ? a0H : (j == 1) ? a1H : (j == 2) ? a2H : a3H;
            if (mI < 2) {
                int col = (tb + j)*16 + c;
                #pragma unroll
                for (int r = 0; r < 4; ++r) {
                    int row0 = 4*g + r, row1 = row0 + 16;
                    *(ushortT*)(osb + ((row0*512 + col*2) ^ ((row0 & 7) << 4))) = f2bf(lo[r]);
                    *(ushortT*)(osb + ((row1*512 + col*2) ^ ((row1 & 7) << 4))) = f2bf(hi[r]);
                }
            } else {
                int hd = (tb + j)*16 + c;
                #pragma unroll
                for (int r = 0; r < 4; ++r) {
                    int rlo = 4*g + r, rhi = rlo + 16;
                    *(ushortT*)(osb + ((hd*64 + rlo*2) ^ ((hd & 3) << 4))) = f2bf(lo[r]);
                    *(ushortT*)(osb + ((hd*64 + rhi*2) ^ ((hd & 3) << 4))) = f2bf(hi[r]);
                }
            }
        }
        __syncthreads();
        if (mI < 2) {
            ushortT* O = (mI == 0) ? qo : ko;
            #pragma unroll
            for (int i = 0; i < 4; ++i) {
                int idx = tid + i*256;            // 1024 16B chunks
                int row = idx >> 5, c16 = idx & 31;
                uint4 vd = *(const uint4*)(osb + ((row*512 + c16*16) ^ ((row & 7) << 4)));
                int hh = c16 >> 2, dq = (c16 & 3) * 8;
                size_t ga = ((size_t)(s*H_ + hh) * R_ + rl0 + row) * D_ + dq;
                *(uint4*)&O[ga] = vd;
            }
        } else {
            #pragma unroll
            for (int i = 0; i < 4; ++i) {
                int idx = tid + i*256;
                int hd = idx >> 2, q8 = idx & 3;
                uint4 vd = *(const uint4*)(osb + ((hd*64 + q8*16) ^ ((hd & 3) << 4)));
                size_t ga = ((size_t)(s*256 + hd)) * R_ + rl0 + q8*8;
                *(uint4*)&vto[ga] = vd;
            }
        }
        __syncthreads();
    }
}

// ---------------------------------------------------------------------------
// K3: attention per (s,h), MFMA. 8 waves, 3 q-tiles each. unroll-2 kb loop
// (prevents hoist-spill), 80B-pitch K rows, parity-double-buffered P slab.
// ---------------------------------------------------------------------------
__global__ __launch_bounds__(512) void k_attn(
        const ushortT* __restrict__ qws, const ushortT* __restrict__ kws,
        const ushortT* __restrict__ vtws, const ushortT* __restrict__ zws,
        const float* __restrict__ mask, float* __restrict__ out) {
    __shared__ ushortT k_sh[R_ * 40];             // [k][d] rows padded to 80 B
    __shared__ ushortT vt_sh[D_ * R_];            // [d][k] XOR ((d&7)<<4)
    __shared__ float   mb[R_];
    __shared__ ushortT p_sh[8 * 1280];            // per-wave dbuf slab [2][16][40]
    int tid = threadIdx.x, wave = tid >> 6, lane = tid & 63;
    int c = lane & 15, g = (lane >> 4) & 3;
    int s = blockIdx.x >> 3, h = blockIdx.x & 7;  // h = id&7: one z-slice per XCD
    size_t base = (size_t)(s * H_ + h) * R_ * D_;

    {   // stage K (80B pitch), V^T (swizzled), mask bias
        const uint4* ks = (const uint4*)(kws + base);
        char* kb_ = (char*)k_sh;
        for (int i = tid; i < 1536; i += 512) {
            int row = i >> 2, part = i & 3;
            *(uint4*)(kb_ + row*80 + part*16) = ks[i];
        }
        const uint4* vs = (const uint4*)(vtws + base);
        char* vb = (char*)vt_sh;
        for (int i = tid; i < 1536; i += 512) {
            int d = i / 48, ch = i % 48;
            *(uint4*)(vb + ((d*768 + ch*16) ^ ((d & 7) << 4))) = vs[i];
        }
        for (int j = tid; j < R_; j += 512) mb[j] = 1e9f * (mask[s*R_ + j] - 1.0f);
    }
    __syncthreads();

    const char* ksb = (const char*)k_sh;
    const char* vtb = (const char*)vt_sh;
    char* psb = (char*)p_sh + wave * 2560;
    const f32x4 zero4 = {0.f, 0.f, 0.f, 0.f};

    for (int qt = wave; qt < 24; qt += 8) {
        int q0 = qt * 16;
        bf16x8 qf = *(const bf16x8*)(qws + base + (size_t)(q0 + c) * D_ + 8*g);
        const ushortT* zq = zws + (size_t)h * RRTOT + (size_t)(q0 + c) * R_ + 4*g;

        float sm = 0.f;
        f32x4 o0 = zero4, o1 = zero4;
        #pragma unroll 2
        for (int kb = 0; kb < 12; ++kb) {
            bf16x8 kfA = *(const bf16x8*)(ksb + ((2*kb    )*16 + c)*80 + 16*g);
            bf16x8 kfB = *(const bf16x8*)(ksb + ((2*kb + 1)*16 + c)*80 + 16*g);
            f32x4 pA = __builtin_amdgcn_mfma_f32_16x16x32_bf16(kfA, qf, zero4, 0, 0, 0);
            f32x4 pB = __builtin_amdgcn_mfma_f32_16x16x32_bf16(kfB, qf, zero4, 0, 0, 0);
            float4 mvA = *(const float4*)&mb[(2*kb    )*16 + 4*g];
            float4 mvB = *(const float4*)&mb[(2*kb + 1)*16 + 4*g];
            ushort4 zvA = *(const ushort4*)(zq + (2*kb    )*16);
            ushort4 zvB = *(const ushort4*)(zq + (2*kb + 1)*16);
            pA.x = __expf(pA.x + mvA.x + bf2f(zvA.x));
            pA.y = __expf(pA.y + mvA.y + bf2f(zvA.y));
            pA.z = __expf(pA.z + mvA.z + bf2f(zvA.z));
            pA.w = __expf(pA.w + mvA.w + bf2f(zvA.w));
            pB.x = __expf(pB.x + mvB.x + bf2f(zvB.x));
            pB.y = __expf(pB.y + mvB.y + bf2f(zvB.y));
            pB.z = __expf(pB.z + mvB.z + bf2f(zvB.z));
            pB.w = __expf(pB.w + mvB.w + bf2f(zvB.w));
            sm += (pA.x + pA.y) + (pA.z + pA.w) + (pB.x + pB.y) + (pB.z + pB.w);
            uint2 wA; wA.x = pack_bf2(pA.x, pA.y); wA.y = pack_bf2(pA.z, pA.w);
            uint2 wB; wB.x = pack_bf2(pB.x, pB.y); wB.y = pack_bf2(pB.z, pB.w);
            *(uint2*)(psb + (kb&1)*1280 + c*80 +      8*g) = wA;
            *(uint2*)(psb + (kb&1)*1280 + c*80 + 32 + 8*g) = wB;
            bf16x8 pa = *(const bf16x8*)(psb + (kb&1)*1280 + c*80 + 16*g);
            bf16x8 v0 = *(const bf16x8*)(vtb + (((c     )*768 + kb*64 + 16*g) ^ ((c & 7) << 4)));
            bf16x8 v1 = *(const bf16x8*)(vtb + (((16 + c)*768 + kb*64 + 16*g) ^ ((c & 7) << 4)));
            o0 = __builtin_amdgcn_mfma_f32_16x16x32_bf16(v0, pa, o0, 0, 0, 0);
            o1 = __builtin_amdgcn_mfma_f32_16x16x32_bf16(v1, pa, o1, 0, 0, 0);
        }
        sm += __shfl_xor(sm, 16);
        sm += __shfl_xor(sm, 32);
        float inv = 1.0f / sm;
        float4 s0, s1;
        s0.x = o0[0]*inv; s0.y = o0[1]*inv; s0.z = o0[2]*inv; s0.w = o0[3]*inv;
        s1.x = o1[0]*inv; s1.y = o1[1]*inv; s1.z = o1[2]*inv; s1.w = o1[3]*inv;
        float* ob = out + (size_t)(s*R_ + q0 + c) * CM + h*D_ + 4*g;
        *(float4*)ob = s0;
        *(float4*)(ob + 16) = s1;
    }
}

// ---------------------------------------------------------------------------
// K4: gating + output projection via MFMA, in-place on d_out. 32 rows/block.
// Each GEMM phase: wave does 4 col-tiles in ONE group (16 tiles / 4 waves).
// ---------------------------------------------------------------------------
__global__ __launch_bounds__(256) void k_out(
        const float* __restrict__ msa, const float* __restrict__ qn_g,
        const float* __restrict__ qn_b, const ushortT* __restrict__ wgt,
        const float* __restrict__ bg, const ushortT* __restrict__ wot,
        const float* __restrict__ bo, float* __restrict__ out) {
    __shared__ ushortT m_sh[32 * 256];
    __shared__ ushortT og_sh[32 * 256];
    int tid = threadIdx.x, wave = tid >> 6, lane = tid & 63;
    int c = lane & 15, g = (lane >> 4) & 3;
    int r0 = blockIdx.x * 32;
    char* msb = (char*)m_sh;
    char* ogb = (char*)og_sh;

    #pragma unroll
    for (int i = 0; i < 8; ++i) {                 // LN
        int row = wave * 8 + i;
        ln_row_f4(msa + (size_t)(r0 + row) * CM, qn_g, qn_b, msb, row, lane);
    }
    __syncthreads();

    bf16x8 af[2][8];
    #pragma unroll
    for (int rt = 0; rt < 2; ++rt)
        #pragma unroll
        for (int kc = 0; kc < 8; ++kc) {
            int row = rt*16 + c;
            af[rt][kc] = *(const bf16x8*)(msb + ((row*512 + (kc*32 + 8*g)*2) ^ ((c & 7) << 4)));
        }

    const f32x4 z4 = {0.f, 0.f, 0.f, 0.f};
    // gating GEMM (4 tiles / wave, one group) + o*g -> og_sh
    {
        int tb = wave * 4;
        const ushortT* wb0 = wgt + (size_t)(tb*16 + c) * 256 + 8*g;
        const ushortT* wb1 = wb0 + 16*256;
        const ushortT* wb2 = wb0 + 32*256;
        const ushortT* wb3 = wb0 + 48*256;
        f32x4 a0L = z4, a0H = z4, a1L = z4, a1H = z4;
        f32x4 a2L = z4, a2H = z4, a3L = z4, a3H = z4;
        #pragma unroll
        for (int kc = 0; kc < 8; ++kc) {
            bf16x8 b0 = *(const bf16x8*)(wb0 + kc*32);
            bf16x8 b1 = *(const bf16x8*)(wb1 + kc*32);
            bf16x8 b2 = *(const bf16x8*)(wb2 + kc*32);
            bf16x8 b3 = *(const bf16x8*)(wb3 + kc*32);
            a0L = __builtin_amdgcn_mfma_f32_16x16x32_bf16(af[0][kc], b0, a0L, 0, 0, 0);
            a0H = __builtin_amdgcn_mfma_f32_16x16x32_bf16(af[1][kc], b0, a0H, 0, 0, 0);
            a1L = __builtin_amdgcn_mfma_f32_16x16x32_bf16(af[0][kc], b1, a1L, 0, 0, 0);
            a1H = __builtin_amdgcn_mfma_f32_16x16x32_bf16(af[1][kc], b1, a1H, 0, 0, 0);
            a2L = __builtin_amdgcn_mfma_f32_16x16x32_bf16(af[0][kc], b2, a2L, 0, 0, 0);
            a2H = __builtin_amdgcn_mfma_f32_16x16x32_bf16(af[1][kc], b2, a2H, 0, 0, 0);
            a3L = __builtin_amdgcn_mfma_f32_16x16x32_bf16(af[0][kc], b3, a3L, 0, 0, 0);
            a3H = __builtin_amdgcn_mfma_f32_16x16x32_bf16(af[1][kc], b3, a3H, 0, 0, 0);
        }
        #pragma unroll
        for (int j = 0; j < 4; ++j) {
            f32x4 lo = (j == 0) ? a0L : (j == 1) ? a1L : (j == 2) ? a2L : a3L;
            f32x4 hi = (j == 0) ? a0H : (j == 1) ? a1H : (j == 2) ? a2H : a3H;
            int t = (tb + j)*16 + c;
            float bgv = bg[t];
            #pragma unroll
            for (int r = 0; r < 4; ++r) {
                int row0 = 4*g + r, row1 = row0 + 16;
                float g0 = 1.0f / (1.0f + __expf(-(lo[r] + bgv)));
                float g1 = 1.0f / (1.0f + __expf(-(hi[r] + bgv)));
                float ov0 = out[(size_t)(r0 + row0) * CM + t];
                float ov1 = out[(size_t)(r0 + row1) * CM + t];
                *(ushortT*)(ogb + ((row0*512 + t*2) ^ ((row0 & 7) << 4))) = f2bf(ov0 * g0);
                *(ushortT*)(ogb + ((row1*512 + t*2) ^ ((row1 & 7) << 4))) = f2bf(ov1 * g1);
            }
        }
    }
    __syncthreads();

    bf16x8 af2[2][8];
    #pragma unroll
    for (int rt = 0; rt < 2; ++rt)
        #pragma unroll
        for (int kc = 0; kc < 8; ++kc) {
            int row = rt*16 + c;
            af2[rt][kc] = *(const bf16x8*)(ogb + ((row*512 + (kc*32 + 8*g)*2) ^ ((c & 7) << 4)));
        }

    {
        int tb = wave * 4;
        const ushortT* wb0 = wot + (size_t)(tb*16 + c) * 256 + 8*g;
        const ushortT* wb1 = wb0 + 16*256;
        const ushortT* wb2 = wb0 + 32*256;
        const ushortT* wb3 = wb0 + 48*256;
        f32x4 a0L = z4, a0H = z4, a1L = z4, a1H = z4;
        f32x4 a2L = z4, a2H = z4, a3L = z4, a3H = z4;
        #pragma unroll
        for (int kc = 0; kc < 8; ++kc) {
            bf16x8 b0 = *(const bf16x8*)(wb0 + kc*32);
            bf16x8 b1 = *(const bf16x8*)(wb1 + kc*32);
            bf16x8 b2 = *(const bf16x8*)(wb2 + kc*32);
            bf16x8 b3 = *(const bf16x8*)(wb3 + kc*32);
            a0L = __builtin_amdgcn_mfma_f32_16x16x32_bf16(af2[0][kc], b0, a0L, 0, 0, 0);
            a0H = __builtin_amdgcn_mfma_f32_16x16x32_bf16(af2[1][kc], b0, a0H, 0, 0, 0);
            a1L = __builtin_amdgcn_mfma_f32_16x16x32_bf16(af2[0][kc], b1, a1L, 0, 0, 0);
            a1H = __builtin_amdgcn_mfma_f32_16x16x32_bf16(af2[1][kc], b1, a1H, 0, 0, 0);
            a2L = __builtin_amdgcn_mfma_f32_16x16x32_bf16(af2[0][kc], b2, a2L, 0, 0, 0);
            a2H = __builtin_amdgcn_mfma_f32_16x16x32_bf16(af2[1][kc], b2, a2H, 0, 0, 0);
            a3L = __builtin_amdgcn_mfma_f32_16x16x32_bf16(af2[0][kc], b3, a3L, 0, 0, 0);
            a3H = __builtin_amdgcn_mfma_f32_16x16x32_bf16(af2[1][kc], b3, a3H, 0, 0, 0);
        }
        #pragma unroll
        for (int j = 0; j < 4; ++j) {
            f32x4 lo = (j == 0) ? a0L : (j == 1) ? a1L : (j == 2) ? a2L : a3L;
            f32x4 hi = (j == 0) ? a0H : (j == 1) ? a1H : (j == 2) ? a2H : a3H;
            int t = (tb + j)*16 + c;
            float bov = bo[t];
            #pragma unroll
            for (int r = 0; r < 4; ++r) {
                int row0 = 4*g + r, row1 = row0 + 16;
                out[(size_t)(r0 + row0) * CM + t] = lo[r] + bov;
                out[(size_t)(r0 + row1) * CM + t] = hi[r] + bov;
            }
        }
    }
}

// ---------------------------------------------------------------------------
extern "C" void kernel_launch(void* const* d_in, const int* in_sizes, int n_in,
                              void* d_out, int out_size, void* d_ws, size_t ws_size,
                              hipStream_t stream) {
    const float* msa    = (const float*)d_in[0];
    const float* pair   = (const float*)d_in[1];
    const float* mask   = (const float*)d_in[2];
    const float* qn_g   = (const float*)d_in[3];
    const float* qn_b   = (const float*)d_in[4];
    const float* pn_g   = (const float*)d_in[5];
    const float* pn_b   = (const float*)d_in[6];
    const float* w_pair = (const float*)d_in[7];
    const float* wq     = (const float*)d_in[8];
    const float* wk     = (const float*)d_in[9];
    const float* wv     = (const float*)d_in[10];
    const float* wg     = (const float*)d_in[11];
    const float* bg     = (const float*)d_in[12];
    const float* wo     = (const float*)d_in[13];
    const float* bo     = (const float*)d_in[14];
    float* out = (float*)d_out;

    ushortT* qws  = (ushortT*)d_ws;
    ushortT* kws  = qws + (size_t)SHRD;
    ushortT* vtws = kws + (size_t)SHRD;
    ushortT* zws  = vtws + (size_t)SHRD;
    ushortT* wt   = zws + (size_t)H_ * RRTOT;
    ushortT* wgt  = wt + 3 * 65536;
    ushortT* wot  = wgt + 65536;

    k_prep     <<<1280,    256, 0, stream>>>(wq, wk, wv, wg, wo, wt, wgt, wot);
    k_pair_bias<<<RRTOT/4, 256, 0, stream>>>(pair, pn_g, pn_b, w_pair, zws);
    k_msa_qkv  <<<SR/32,   256, 0, stream>>>(msa, qn_g, qn_b, wt, qws, kws, vtws);
    k_attn     <<<S_*H_,   512, 0, stream>>>(qws, kws, vtws, zws, mask, out);
    k_out      <<<SR/32,   256, 0, stream>>>(msa, qn_g, qn_b, wgt, bg, wot, bo, out);
}

// Round 10
// 273.823 us; speedup vs baseline: 1.0496x; 1.0496x over previous
//
#include <hip/hip_runtime.h>
#include <hip/hip_bf16.h>

typedef unsigned int uint;
typedef unsigned short ushortT;
typedef __attribute__((ext_vector_type(8))) short bf16x8;
typedef __attribute__((ext_vector_type(4))) float f32x4;

#define S_ 128
#define R_ 384
#define CM 256
#define CZ 128
#define H_ 8
#define D_ 32
#define SR (S_*R_)          // 49152
#define RRTOT (R_*R_)       // 147456
#define SHRD (S_*H_*R_*D_)  // 12582912 elements

__device__ __forceinline__ float bf2f(ushortT u) {
    return __uint_as_float(((uint)u) << 16);
}
__device__ __forceinline__ ushortT f2bf(float f) {
    uint x = __float_as_uint(f);
    x += 0x7FFFu + ((x >> 16) & 1u);   // RNE
    return (ushortT)(x >> 16);
}
__device__ __forceinline__ uint pack_bf2(float lo, float hi) {
    return (uint)f2bf(lo) | ((uint)f2bf(hi) << 16);
}

// ---------------------------------------------------------------------------
// K0: weight prep — transpose + bf16-ify all projection weights.
// ---------------------------------------------------------------------------
__global__ __launch_bounds__(256) void k_prep(
        const float* __restrict__ wq, const float* __restrict__ wk,
        const float* __restrict__ wv, const float* __restrict__ wg,
        const float* __restrict__ wo,
        ushortT* __restrict__ wt, ushortT* __restrict__ wgt,
        ushortT* __restrict__ wot) {
    int id = blockIdx.x * 256 + threadIdx.x;      // 5*65536 total
    int which = id >> 16, r16 = id & 65535;
    int y = r16 & 255, x = r16 >> 8;              // y = coalesced src fast dim
    if (which == 0)      wt[(size_t)y*256 + x]       = f2bf(wq[(size_t)x*256 + y] * 0.17677669529663687f);
    else if (which == 1) wt[(size_t)(256+y)*256 + x] = f2bf(wk[(size_t)x*256 + y]);
    else if (which == 2) wt[(size_t)(512+y)*256 + x] = f2bf(wv[(size_t)x*256 + y]);
    else if (which == 3) wgt[(size_t)y*256 + x]      = f2bf(wg[(size_t)x*256 + y]);
    else                 wot[(size_t)y*256 + x]      = f2bf(wo[(size_t)x*256 + y]);
}

// ---------------------------------------------------------------------------
// K1: pair LN + projection to z[h][i][j] (bf16). One wave per (i,j) row.
// ---------------------------------------------------------------------------
__global__ __launch_bounds__(256) void k_pair_bias(
        const float* __restrict__ pair, const float* __restrict__ pn_g,
        const float* __restrict__ pn_b, const float* __restrict__ w_pair,
        ushortT* __restrict__ z) {
    int wave = threadIdx.x >> 6, lane = threadIdx.x & 63;
    int row = blockIdx.x * 4 + wave;              // [0, R*R)
    const float* x = pair + (size_t)row * CZ;
    float2 xv = *(const float2*)&x[lane * 2];
    float s  = xv.x + xv.y;
    float s2 = xv.x*xv.x + xv.y*xv.y;
    #pragma unroll
    for (int off = 32; off; off >>= 1) {
        s  += __shfl_xor(s,  off);
        s2 += __shfl_xor(s2, off);
    }
    float mu  = s * (1.0f / 128.0f);
    float var = s2 * (1.0f / 128.0f) - mu * mu;
    float rstd = rsqrtf(var + 1e-5f);
    float2 gv = *(const float2*)&pn_g[lane * 2];
    float2 bv = *(const float2*)&pn_b[lane * 2];
    float n0 = (xv.x - mu) * rstd * gv.x + bv.x;
    float n1 = (xv.y - mu) * rstd * gv.y + bv.y;
    float4 wa = *(const float4*)&w_pair[lane*16     ];
    float4 wb = *(const float4*)&w_pair[lane*16 +  4];
    float4 wc = *(const float4*)&w_pair[lane*16 +  8];
    float4 wd = *(const float4*)&w_pair[lane*16 + 12];
    float v0_ = n0*wa.x + n1*wc.x, v1_ = n0*wa.y + n1*wc.y;
    float v2_ = n0*wa.z + n1*wc.z, v3_ = n0*wa.w + n1*wc.w;
    float v4_ = n0*wb.x + n1*wd.x, v5_ = n0*wb.y + n1*wd.y;
    float v6_ = n0*wb.z + n1*wd.z, v7_ = n0*wb.w + n1*wd.w;
    float x0 = __shfl_xor(v0_,1), x1 = __shfl_xor(v1_,1), x2 = __shfl_xor(v2_,1), x3 = __shfl_xor(v3_,1);
    float x4 = __shfl_xor(v4_,1), x5 = __shfl_xor(v5_,1), x6 = __shfl_xor(v6_,1), x7 = __shfl_xor(v7_,1);
    bool b0 = (lane & 1) != 0;
    float u0 = b0 ? v4_+x4 : v0_+x0;
    float u1 = b0 ? v5_+x5 : v1_+x1;
    float u2 = b0 ? v6_+x6 : v2_+x2;
    float u3 = b0 ? v7_+x7 : v3_+x3;
    float y0 = __shfl_xor(u0,2), y1 = __shfl_xor(u1,2), y2 = __shfl_xor(u2,2), y3 = __shfl_xor(u3,2);
    bool b1 = (lane & 2) != 0;
    float w0 = b1 ? u2+y2 : u0+y0;
    float w1 = b1 ? u3+y3 : u1+y1;
    float z0 = __shfl_xor(w0,4), z1 = __shfl_xor(w1,4);
    bool b2 = (lane & 4) != 0;
    float val = b2 ? w1+z1 : w0+z0;
    val += __shfl_xor(val, 8);
    val += __shfl_xor(val, 16);
    val += __shfl_xor(val, 32);
    int hmap = 4*(lane & 1) + 2*((lane >> 1) & 1) + ((lane >> 2) & 1);
    if (lane < 8) z[(size_t)hmap * RRTOT + row] = f2bf(val);
}

// ---------------------------------------------------------------------------
// LN helper: fused sum/sum^2 single butterfly (E[x^2]-mu^2), float4 loads,
// writes verified XOR-swizzled bf16 layout.
// ---------------------------------------------------------------------------
__device__ __forceinline__ void ln_row_f4(
        const float* __restrict__ src, const float* __restrict__ gam,
        const float* __restrict__ bet, char* msb, int row, int lane) {
    float4 xv = *(const float4*)&src[lane * 4];
    float sm = (xv.x + xv.y) + (xv.z + xv.w);
    float s2 = (xv.x*xv.x + xv.y*xv.y) + (xv.z*xv.z + xv.w*xv.w);
    #pragma unroll
    for (int off = 32; off; off >>= 1) {
        sm += __shfl_xor(sm, off);
        s2 += __shfl_xor(s2, off);
    }
    float mu  = sm * (1.0f / 256.0f);
    float var = s2 * (1.0f / 256.0f) - mu * mu;
    float rstd = rsqrtf(var + 1e-5f);
    float4 gv = *(const float4*)&gam[lane * 4];
    float4 bv = *(const float4*)&bet[lane * 4];
    float n0 = (xv.x - mu) * rstd * gv.x + bv.x, n1 = (xv.y - mu) * rstd * gv.y + bv.y;
    float n2 = (xv.z - mu) * rstd * gv.z + bv.z, n3 = (xv.w - mu) * rstd * gv.w + bv.w;
    uint2 w; w.x = pack_bf2(n0, n1); w.y = pack_bf2(n2, n3);
    *(uint2*)(msb + ((row*512 + lane*8) ^ ((row & 7) << 4))) = w;
}

// ---------------------------------------------------------------------------
// K2: MSA LN + Q/K/V projections via MFMA. 32 rows/block, 4 waves.
// Restructured phase graph: 3 MFMA groups run back-to-back with ZERO interior
// barriers, each staging into its OWN 16KB LDS region; ONE barrier; then one
// store phase (12 independent uint4 stores/thread). Removes the 3 per-mI
// vmcnt(0) barrier drains that serialized r8/r9. Layouts byte-identical.
// ---------------------------------------------------------------------------
__global__ __launch_bounds__(256) void k_msa_qkv(
        const float* __restrict__ msa, const float* __restrict__ qn_g,
        const float* __restrict__ qn_b, const ushortT* __restrict__ wt,
        ushortT* __restrict__ qo, ushortT* __restrict__ ko,
        ushortT* __restrict__ vto) {
    __shared__ ushortT m_sh[32 * 256];            // LN'd input, XOR (row&7)<<4
    __shared__ ushortT st_sh[3 * 32 * 256];       // staging: q | k | v^T regions
    int tid = threadIdx.x, wave = tid >> 6, lane = tid & 63;
    int c = lane & 15, g = (lane >> 4) & 3;
    int r0 = blockIdx.x * 32, s = r0 / R_, rl0 = r0 % R_;
    char* msb = (char*)m_sh;
    char* stb = (char*)st_sh;

    #pragma unroll
    for (int i = 0; i < 8; ++i) {                 // LN: wave handles 8 rows
        int row = wave * 8 + i;
        ln_row_f4(msa + (size_t)(r0 + row) * CM, qn_g, qn_b, msb, row, lane);
    }
    __syncthreads();

    bf16x8 af[2][8];
    #pragma unroll
    for (int rt = 0; rt < 2; ++rt)
        #pragma unroll
        for (int kc = 0; kc < 8; ++kc) {
            int row = rt*16 + c;
            af[rt][kc] = *(const bf16x8*)(msb + ((row*512 + (kc*32 + 8*g)*2) ^ ((c & 7) << 4)));
        }

    const f32x4 z4 = {0.f, 0.f, 0.f, 0.f};
    #pragma unroll
    for (int mI = 0; mI < 3; ++mI) {
        char* osb = stb + mI * 16384;
        int tb = wave * 4;                        // tiles tb..tb+3
        const ushortT* wb0 = wt + ((size_t)(mI*256 + tb*16 + c)) * 256 + 8*g;
        const ushortT* wb1 = wb0 + 16*256;
        const ushortT* wb2 = wb0 + 32*256;
        const ushortT* wb3 = wb0 + 48*256;
        f32x4 a0L = z4, a0H = z4, a1L = z4, a1H = z4;
        f32x4 a2L = z4, a2H = z4, a3L = z4, a3H = z4;
        #pragma unroll
        for (int kc = 0; kc < 8; ++kc) {
            bf16x8 b0 = *(const bf16x8*)(wb0 + kc*32);
            bf16x8 b1 = *(const bf16x8*)(wb1 + kc*32);
            bf16x8 b2 = *(const bf16x8*)(wb2 + kc*32);
            bf16x8 b3 = *(const bf16x8*)(wb3 + kc*32);
            a0L = __builtin_amdgcn_mfma_f32_16x16x32_bf16(af[0][kc], b0, a0L, 0, 0, 0);
            a0H = __builtin_amdgcn_mfma_f32_16x16x32_bf16(af[1][kc], b0, a0H, 0, 0, 0);
            a1L = __builtin_amdgcn_mfma_f32_16x16x32_bf16(af[0][kc], b1, a1L, 0, 0, 0);
            a1H = __builtin_amdgcn_mfma_f32_16x16x32_bf16(af[1][kc], b1, a1H, 0, 0, 0);
            a2L = __builtin_amdgcn_mfma_f32_16x16x32_bf16(af[0][kc], b2, a2L, 0, 0, 0);
            a2H = __builtin_amdgcn_mfma_f32_16x16x32_bf16(af[1][kc], b2, a2H, 0, 0, 0);
            a3L = __builtin_amdgcn_mfma_f32_16x16x32_bf16(af[0][kc], b3, a3L, 0, 0, 0);
            a3H = __builtin_amdgcn_mfma_f32_16x16x32_bf16(af[1][kc], b3, a3H, 0, 0, 0);
        }
        #pragma unroll
        for (int j = 0; j < 4; ++j) {
            f32x4 lo = (j == 0) ? a0L : (j == 1) ? a1L : (j == 2) ? a2L : a3L;
            f32x4 hi = (j == 0) ? a0H : (j == 1) ? a1H : (j == 2) ? a2H : a3H;
            if (mI < 2) {
                int col = (tb + j)*16 + c;
                #pragma unroll
                for (int r = 0; r < 4; ++r) {
                    int row0 = 4*g + r, row1 = row0 + 16;
                    *(ushortT*)(osb + ((row0*512 + col*2) ^ ((row0 & 7) << 4))) = f2bf(lo[r]);
                    *(ushortT*)(osb + ((row1*512 + col*2) ^ ((row1 & 7) << 4))) = f2bf(hi[r]);
                }
            } else {
                int hd = (tb + j)*16 + c;
                #pragma unroll
                for (int r = 0; r < 4; ++r) {
                    int rlo = 4*g + r, rhi = rlo + 16;
                    *(ushortT*)(osb + ((hd*64 + rlo*2) ^ ((hd & 3) << 4))) = f2bf(lo[r]);
                    *(ushortT*)(osb + ((hd*64 + rhi*2) ^ ((hd & 3) << 4))) = f2bf(hi[r]);
                }
            }
        }
    }
    __syncthreads();                               // single barrier before stores

    // store q and k (regions 0,1): 4 uint4/thread each
    #pragma unroll
    for (int m = 0; m < 2; ++m) {
        char* osb = stb + m * 16384;
        ushortT* O = (m == 0) ? qo : ko;
        #pragma unroll
        for (int i = 0; i < 4; ++i) {
            int idx = tid + i*256;                // 1024 16B chunks
            int row = idx >> 5, c16 = idx & 31;
            uint4 vd = *(const uint4*)(osb + ((row*512 + c16*16) ^ ((row & 7) << 4)));
            int hh = c16 >> 2, dq = (c16 & 3) * 8;
            size_t ga = ((size_t)(s*H_ + hh) * R_ + rl0 + row) * D_ + dq;
            *(uint4*)&O[ga] = vd;
        }
    }
    {   // store v^T (region 2)
        char* osb = stb + 2 * 16384;
        #pragma unroll
        for (int i = 0; i < 4; ++i) {
            int idx = tid + i*256;
            int hd = idx >> 2, q8 = idx & 3;
            uint4 vd = *(const uint4*)(osb + ((hd*64 + q8*16) ^ ((hd & 3) << 4)));
            size_t ga = ((size_t)(s*256 + hd)) * R_ + rl0 + q8*8;
            *(uint4*)&vto[ga] = vd;
        }
    }
}

// ---------------------------------------------------------------------------
// K3: attention per (s,h), MFMA. 8 waves, 3 q-tiles each. unroll-2 kb loop
// (prevents hoist-spill), 80B-pitch K rows, parity-double-buffered P slab.
// ---------------------------------------------------------------------------
__global__ __launch_bounds__(512) void k_attn(
        const ushortT* __restrict__ qws, const ushortT* __restrict__ kws,
        const ushortT* __restrict__ vtws, const ushortT* __restrict__ zws,
        const float* __restrict__ mask, float* __restrict__ out) {
    __shared__ ushortT k_sh[R_ * 40];             // [k][d] rows padded to 80 B
    __shared__ ushortT vt_sh[D_ * R_];            // [d][k] XOR ((d&7)<<4)
    __shared__ float   mb[R_];
    __shared__ ushortT p_sh[8 * 1280];            // per-wave dbuf slab [2][16][40]
    int tid = threadIdx.x, wave = tid >> 6, lane = tid & 63;
    int c = lane & 15, g = (lane >> 4) & 3;
    int s = blockIdx.x >> 3, h = blockIdx.x & 7;  // h = id&7: one z-slice per XCD
    size_t base = (size_t)(s * H_ + h) * R_ * D_;

    {   // stage K (80B pitch), V^T (swizzled), mask bias
        const uint4* ks = (const uint4*)(kws + base);
        char* kb_ = (char*)k_sh;
        for (int i = tid; i < 1536; i += 512) {
            int row = i >> 2, part = i & 3;
            *(uint4*)(kb_ + row*80 + part*16) = ks[i];
        }
        const uint4* vs = (const uint4*)(vtws + base);
        char* vb = (char*)vt_sh;
        for (int i = tid; i < 1536; i += 512) {
            int d = i / 48, ch = i % 48;
            *(uint4*)(vb + ((d*768 + ch*16) ^ ((d & 7) << 4))) = vs[i];
        }
        for (int j = tid; j < R_; j += 512) mb[j] = 1e9f * (mask[s*R_ + j] - 1.0f);
    }
    __syncthreads();

    const char* ksb = (const char*)k_sh;
    const char* vtb = (const char*)vt_sh;
    char* psb = (char*)p_sh + wave * 2560;
    const f32x4 zero4 = {0.f, 0.f, 0.f, 0.f};

    for (int qt = wave; qt < 24; qt += 8) {
        int q0 = qt * 16;
        bf16x8 qf = *(const bf16x8*)(qws + base + (size_t)(q0 + c) * D_ + 8*g);
        const ushortT* zq = zws + (size_t)h * RRTOT + (size_t)(q0 + c) * R_ + 4*g;

        float sm = 0.f;
        f32x4 o0 = zero4, o1 = zero4;
        #pragma unroll 2
        for (int kb = 0; kb < 12; ++kb) {
            bf16x8 kfA = *(const bf16x8*)(ksb + ((2*kb    )*16 + c)*80 + 16*g);
            bf16x8 kfB = *(const bf16x8*)(ksb + ((2*kb + 1)*16 + c)*80 + 16*g);
            f32x4 pA = __builtin_amdgcn_mfma_f32_16x16x32_bf16(kfA, qf, zero4, 0, 0, 0);
            f32x4 pB = __builtin_amdgcn_mfma_f32_16x16x32_bf16(kfB, qf, zero4, 0, 0, 0);
            float4 mvA = *(const float4*)&mb[(2*kb    )*16 + 4*g];
            float4 mvB = *(const float4*)&mb[(2*kb + 1)*16 + 4*g];
            ushort4 zvA = *(const ushort4*)(zq + (2*kb    )*16);
            ushort4 zvB = *(const ushort4*)(zq + (2*kb + 1)*16);
            pA.x = __expf(pA.x + mvA.x + bf2f(zvA.x));
            pA.y = __expf(pA.y + mvA.y + bf2f(zvA.y));
            pA.z = __expf(pA.z + mvA.z + bf2f(zvA.z));
            pA.w = __expf(pA.w + mvA.w + bf2f(zvA.w));
            pB.x = __expf(pB.x + mvB.x + bf2f(zvB.x));
            pB.y = __expf(pB.y + mvB.y + bf2f(zvB.y));
            pB.z = __expf(pB.z + mvB.z + bf2f(zvB.z));
            pB.w = __expf(pB.w + mvB.w + bf2f(zvB.w));
            sm += (pA.x + pA.y) + (pA.z + pA.w) + (pB.x + pB.y) + (pB.z + pB.w);
            uint2 wA; wA.x = pack_bf2(pA.x, pA.y); wA.y = pack_bf2(pA.z, pA.w);
            uint2 wB; wB.x = pack_bf2(pB.x, pB.y); wB.y = pack_bf2(pB.z, pB.w);
            *(uint2*)(psb + (kb&1)*1280 + c*80 +      8*g) = wA;
            *(uint2*)(psb + (kb&1)*1280 + c*80 + 32 + 8*g) = wB;
            bf16x8 pa = *(const bf16x8*)(psb + (kb&1)*1280 + c*80 + 16*g);
            bf16x8 v0 = *(const bf16x8*)(vtb + (((c     )*768 + kb*64 + 16*g) ^ ((c & 7) << 4)));
            bf16x8 v1 = *(const bf16x8*)(vtb + (((16 + c)*768 + kb*64 + 16*g) ^ ((c & 7) << 4)));
            o0 = __builtin_amdgcn_mfma_f32_16x16x32_bf16(v0, pa, o0, 0, 0, 0);
            o1 = __builtin_amdgcn_mfma_f32_16x16x32_bf16(v1, pa, o1, 0, 0, 0);
        }
        sm += __shfl_xor(sm, 16);
        sm += __shfl_xor(sm, 32);
        float inv = 1.0f / sm;
        float4 s0, s1;
        s0.x = o0[0]*inv; s0.y = o0[1]*inv; s0.z = o0[2]*inv; s0.w = o0[3]*inv;
        s1.x = o1[0]*inv; s1.y = o1[1]*inv; s1.z = o1[2]*inv; s1.w = o1[3]*inv;
        float* ob = out + (size_t)(s*R_ + q0 + c) * CM + h*D_ + 4*g;
        *(float4*)ob = s0;
        *(float4*)(ob + 16) = s1;
    }
}

// ---------------------------------------------------------------------------
// K4: gating + output projection via MFMA, in-place on d_out. 32 rows/block.
// ---------------------------------------------------------------------------
__global__ __launch_bounds__(256) void k_out(
        const float* __restrict__ msa, const float* __restrict__ qn_g,
        const float* __restrict__ qn_b, const ushortT* __restrict__ wgt,
        const float* __restrict__ bg, const ushortT* __restrict__ wot,
        const float* __restrict__ bo, float* __restrict__ out) {
    __shared__ ushortT m_sh[32 * 256];
    __shared__ ushortT og_sh[32 * 256];
    int tid = threadIdx.x, wave = tid >> 6, lane = tid & 63;
    int c = lane & 15, g = (lane >> 4) & 3;
    int r0 = blockIdx.x * 32;
    char* msb = (char*)m_sh;
    char* ogb = (char*)og_sh;

    #pragma unroll
    for (int i = 0; i < 8; ++i) {                 // LN
        int row = wave * 8 + i;
        ln_row_f4(msa + (size_t)(r0 + row) * CM, qn_g, qn_b, msb, row, lane);
    }
    __syncthreads();

    bf16x8 af[2][8];
    #pragma unroll
    for (int rt = 0; rt < 2; ++rt)
        #pragma unroll
        for (int kc = 0; kc < 8; ++kc) {
            int row = rt*16 + c;
            af[rt][kc] = *(const bf16x8*)(msb + ((row*512 + (kc*32 + 8*g)*2) ^ ((c & 7) << 4)));
        }

    const f32x4 z4 = {0.f, 0.f, 0.f, 0.f};
    // gating GEMM (4 tiles / wave, one group) + o*g -> og_sh
    {
        int tb = wave * 4;
        const ushortT* wb0 = wgt + (size_t)(tb*16 + c) * 256 + 8*g;
        const ushortT* wb1 = wb0 + 16*256;
        const ushortT* wb2 = wb0 + 32*256;
        const ushortT* wb3 = wb0 + 48*256;
        f32x4 a0L = z4, a0H = z4, a1L = z4, a1H = z4;
        f32x4 a2L = z4, a2H = z4, a3L = z4, a3H = z4;
        #pragma unroll
        for (int kc = 0; kc < 8; ++kc) {
            bf16x8 b0 = *(const bf16x8*)(wb0 + kc*32);
            bf16x8 b1 = *(const bf16x8*)(wb1 + kc*32);
            bf16x8 b2 = *(const bf16x8*)(wb2 + kc*32);
            bf16x8 b3 = *(const bf16x8*)(wb3 + kc*32);
            a0L = __builtin_amdgcn_mfma_f32_16x16x32_bf16(af[0][kc], b0, a0L, 0, 0, 0);
            a0H = __builtin_amdgcn_mfma_f32_16x16x32_bf16(af[1][kc], b0, a0H, 0, 0, 0);
            a1L = __builtin_amdgcn_mfma_f32_16x16x32_bf16(af[0][kc], b1, a1L, 0, 0, 0);
            a1H = __builtin_amdgcn_mfma_f32_16x16x32_bf16(af[1][kc], b1, a1H, 0, 0, 0);
            a2L = __builtin_amdgcn_mfma_f32_16x16x32_bf16(af[0][kc], b2, a2L, 0, 0, 0);
            a2H = __builtin_amdgcn_mfma_f32_16x16x32_bf16(af[1][kc], b2, a2H, 0, 0, 0);
            a3L = __builtin_amdgcn_mfma_f32_16x16x32_bf16(af[0][kc], b3, a3L, 0, 0, 0);
            a3H = __builtin_amdgcn_mfma_f32_16x16x32_bf16(af[1][kc], b3, a3H, 0, 0, 0);
        }
        #pragma unroll
        for (int j = 0; j < 4; ++j) {
            f32x4 lo = (j == 0) ? a0L : (j == 1) ? a1L : (j == 2) ? a2L : a3L;
            f32x4 hi = (j == 0) ? a0H : (j == 1) ? a1H : (j == 2) ? a2H : a3H;
            int t = (tb + j)*16 + c;
            float bgv = bg[t];
            #pragma unroll
            for (int r = 0; r < 4; ++r) {
                int row0 = 4*g + r, row1 = row0 + 16;
                float g0 = 1.0f / (1.0f + __expf(-(lo[r] + bgv)));
                float g1 = 1.0f / (1.0f + __expf(-(hi[r] + bgv)));
                float ov0 = out[(size_t)(r0 + row0) * CM + t];
                float ov1 = out[(size_t)(r0 + row1) * CM + t];
                *(ushortT*)(ogb + ((row0*512 + t*2) ^ ((row0 & 7) << 4))) = f2bf(ov0 * g0);
                *(ushortT*)(ogb + ((row1*512 + t*2) ^ ((row1 & 7) << 4))) = f2bf(ov1 * g1);
            }
        }
    }
    __syncthreads();

    bf16x8 af2[2][8];
    #pragma unroll
    for (int rt = 0; rt < 2; ++rt)
        #pragma unroll
        for (int kc = 0; kc < 8; ++kc) {
            int row = rt*16 + c;
            af2[rt][kc] = *(const bf16x8*)(ogb + ((row*512 + (kc*32 + 8*g)*2) ^ ((c & 7) << 4)));
        }

    {
        int tb = wave * 4;
        const ushortT* wb0 = wot + (size_t)(tb*16 + c) * 256 + 8*g;
        const ushortT* wb1 = wb0 + 16*256;
        const ushortT* wb2 = wb0 + 32*256;
        const ushortT* wb3 = wb0 + 48*256;
        f32x4 a0L = z4, a0H = z4, a1L = z4, a1H = z4;
        f32x4 a2L = z4, a2H = z4, a3L = z4, a3H = z4;
        #pragma unroll
        for (int kc = 0; kc < 8; ++kc) {
            bf16x8 b0 = *(const bf16x8*)(wb0 + kc*32);
            bf16x8 b1 = *(const bf16x8*)(wb1 + kc*32);
            bf16x8 b2 = *(const bf16x8*)(wb2 + kc*32);
            bf16x8 b3 = *(const bf16x8*)(wb3 + kc*32);
            a0L = __builtin_amdgcn_mfma_f32_16x16x32_bf16(af2[0][kc], b0, a0L, 0, 0, 0);
            a0H = __builtin_amdgcn_mfma_f32_16x16x32_bf16(af2[1][kc], b0, a0H, 0, 0, 0);
            a1L = __builtin_amdgcn_mfma_f32_16x16x32_bf16(af2[0][kc], b1, a1L, 0, 0, 0);
            a1H = __builtin_amdgcn_mfma_f32_16x16x32_bf16(af2[1][kc], b1, a1H, 0, 0, 0);
            a2L = __builtin_amdgcn_mfma_f32_16x16x32_bf16(af2[0][kc], b2, a2L, 0, 0, 0);
            a2H = __builtin_amdgcn_mfma_f32_16x16x32_bf16(af2[1][kc], b2, a2H, 0, 0, 0);
            a3L = __builtin_amdgcn_mfma_f32_16x16x32_bf16(af2[0][kc], b3, a3L, 0, 0, 0);
            a3H = __builtin_amdgcn_mfma_f32_16x16x32_bf16(af2[1][kc], b3, a3H, 0, 0, 0);
        }
        #pragma unroll
        for (int j = 0; j < 4; ++j) {
            f32x4 lo = (j == 0) ? a0L : (j == 1) ? a1L : (j == 2) ? a2L : a3L;
            f32x4 hi = (j == 0) ? a0H : (j == 1) ? a1H : (j == 2) ? a2H : a3H;
            int t = (tb + j)*16 + c;
            float bov = bo[t];
            #pragma unroll
            for (int r = 0; r < 4; ++r) {
                int row0 = 4*g + r, row1 = row0 + 16;
                out[(size_t)(r0 + row0) * CM + t] = lo[r] + bov;
                out[(size_t)(r0 + row1) * CM + t] = hi[r] + bov;
            }
        }
    }
}

// ---------------------------------------------------------------------------
extern "C" void kernel_launch(void* const* d_in, const int* in_sizes, int n_in,
                              void* d_out, int out_size, void* d_ws, size_t ws_size,
                              hipStream_t stream) {
    const float* msa    = (const float*)d_in[0];
    const float* pair   = (const float*)d_in[1];
    const float* mask   = (const float*)d_in[2];
    const float* qn_g   = (const float*)d_in[3];
    const float* qn_b   = (const float*)d_in[4];
    const float* pn_g   = (const float*)d_in[5];
    const float* pn_b   = (const float*)d_in[6];
    const float* w_pair = (const float*)d_in[7];
    const float* wq     = (const float*)d_in[8];
    const float* wk     = (const float*)d_in[9];
    const float* wv     = (const float*)d_in[10];
    const float* wg     = (const float*)d_in[11];
    const float* bg     = (const float*)d_in[12];
    const float* wo     = (const float*)d_in[13];
    const float* bo     = (const float*)d_in[14];
    float* out = (float*)d_out;

    ushortT* qws  = (ushortT*)d_ws;
    ushortT* kws  = qws + (size_t)SHRD;
    ushortT* vtws = kws + (size_t)SHRD;
    ushortT* zws  = vtws + (size_t)SHRD;
    ushortT* wt   = zws + (size_t)H_ * RRTOT;
    ushortT* wgt  = wt + 3 * 65536;
    ushortT* wot  = wgt + 65536;

    k_prep     <<<1280,    256, 0, stream>>>(wq, wk, wv, wg, wo, wt, wgt, wot);
    k_pair_bias<<<RRTOT/4, 256, 0, stream>>>(pair, pn_g, pn_b, w_pair, zws);
    k_msa_qkv  <<<SR/32,   256, 0, stream>>>(msa, qn_g, qn_b, wt, qws, kws, vtws);
    k_attn     <<<S_*H_,   512, 0, stream>>>(qws, kws, vtws, zws, mask, out);
    k_out      <<<SR/32,   256, 0, stream>>>(msa, qn_g, qn_b, wgt, bg, wot, bo, out);
}